// Round 7
// baseline (1238.747 us; speedup 1.0000x reference)
//
#include <hip/hip_runtime.h>
#include <cstdint>
#include <cstddef>

// ---------------------------------------------------------------------------
// Star-Transformer forward on MI355X. R13 = compose the two individually
// proven GEMM fixes (they were never active together):
//  - XCD-affinity swizzle (R12): FETCH 157->56MB (= footprint) on pw_w2.
//  - TM=64 for N=768-class GEMMs (R7/R8): grid 768/2304/1536 = 3/9/6
//    blocks/CU exact balance (R12's TM=128 grid=384 = 1.5/CU, Occ 14%).
// GEMM core unchanged from R12 otherwise: conflict-free chunked K-major LDS
// subtiles (0 measured conflicts), 3-slot rotating LDS, one s_barrier/K-step,
// counted vmcnt(S=TM/64+2), no split-K. pw_w1 stays TM=128/ORDER=1 (6/CU).
// ---------------------------------------------------------------------------

typedef unsigned short u16;
typedef __attribute__((ext_vector_type(4))) float f32x4;
typedef __attribute__((ext_vector_type(8))) __bf16 bf16x8;

#define NB 8
#define SEQ 1024
#define HDIM 768
#define NHEAD 12
#define HD 64
#define DINNER 3072
#define NHID 1024
#define NOUT 5000
#define ATT_SCALE 0.125f

static __device__ __forceinline__ float b2f(u16 u) {
  union { float f; uint32_t i; } v; v.i = ((uint32_t)u) << 16; return v.f;
}
static __device__ __forceinline__ u16 f2b(float f) {
  union { float f; uint32_t i; } v; v.f = f;
  uint32_t r = v.i + 0x7fffu + ((v.i >> 16) & 1u);
  return (u16)(r >> 16);
}
// unpack 2 packed bf16 (one u32) -> 2 floats
static __device__ __forceinline__ float2 b2f2(uint32_t u) {
  union { float f; uint32_t i; } lo, hi;
  lo.i = u << 16; hi.i = u & 0xffff0000u;
  return make_float2(lo.f, hi.f);
}

// async global->LDS, 16B per lane; LDS dest = wave-uniform base + lane*16.
static __device__ __forceinline__ void gl2lds16(const void* g, void* l) {
  __builtin_amdgcn_global_load_lds(
      (__attribute__((address_space(1))) void*)(uintptr_t)g,
      (__attribute__((address_space(3))) void*)l, 16, 0, 0);
}

template <int N>
static __device__ __forceinline__ void wait_vmcnt() {
  if constexpr (N == 0) asm volatile("s_waitcnt vmcnt(0)" ::: "memory");
  else if constexpr (N == 3) asm volatile("s_waitcnt vmcnt(3)" ::: "memory");
  else if constexpr (N == 4) asm volatile("s_waitcnt vmcnt(4)" ::: "memory");
  else if constexpr (N == 8) asm volatile("s_waitcnt vmcnt(8)" ::: "memory");
}

static __device__ __forceinline__ float blk_sum(float v, float* red) {
  #pragma unroll
  for (int off = 32; off > 0; off >>= 1) v += __shfl_down(v, off, 64);
  if ((threadIdx.x & 63) == 0) red[threadIdx.x >> 6] = v;
  __syncthreads();
  float r = red[0] + red[1] + red[2] + red[3];
  __syncthreads();
  return r;
}
static __device__ __forceinline__ float blk_max(float v, float* red) {
  #pragma unroll
  for (int off = 32; off > 0; off >>= 1) v = fmaxf(v, __shfl_down(v, off, 64));
  if ((threadIdx.x & 63) == 0) red[threadIdx.x >> 6] = v;
  __syncthreads();
  float r = fmaxf(fmaxf(red[0], red[1]), fmaxf(red[2], red[3]));
  __syncthreads();
  return r;
}

// ---------------------------------------------------------------------------
// Segmented fp32 -> bf16 converter (up to 4 tensors per dispatch).
// ---------------------------------------------------------------------------
struct Cvt4 {
  const float* s0; const float* s1; const float* s2; const float* s3;
  u16* d0; u16* d1; u16* d2; u16* d3;
  int c1, c2, c3, c4;
};
__global__ __launch_bounds__(256) void cvt4_k(Cvt4 a) {
  const int i = blockIdx.x * 256 + threadIdx.x;
  if (i >= a.c4) return;
  const float* s; u16* d; int j;
  if (i < a.c1)      { s = a.s0; d = a.d0; j = i; }
  else if (i < a.c2) { s = a.s1; d = a.d1; j = i - a.c1; }
  else if (i < a.c3) { s = a.s2; d = a.d2; j = i - a.c2; }
  else               { s = a.s3; d = a.d3; j = i - a.c3; }
  const float4 v = ((const float4*)s)[j];
  ushort4 o;
  o.x = f2b(v.x); o.y = f2b(v.y); o.z = f2b(v.z); o.w = f2b(v.w);
  ((ushort4*)d)[j] = o;
}

// ---------------------------------------------------------------------------
// NT GEMM: C[M,N] = act(A[M,K] . W[N,K]^T + bias[N]).
// 1-D grid of G = NMAT*(N/128)*(M/TM) blocks; XCD-affinity decode:
//   xcd = o&7, j = o>>3; mpx = (M/TM)/8 panels per XCD.
//   ORDER==0 (n-fast):  lp = j / NXB, n = j % NXB  -> all n-blocks of one
//     M-panel run consecutively on one XCD (A-panel L2-resident).
//   ORDER==1 (panel-fast): n = j / mpx, lp = j % mpx (W-block resident).
//   bm = (xcd*mpx+lp)*TM; mat = n / nblk (z-fusion); bn = (n%nblk)*128.
// TM x 128 tile, 4 waves (2x2), wave owns (TM/2) x 64, MI=TM/32 A-frags.
// LDS: chunked K-major per 16-row subtile (R10/R12; 0 measured conflicts):
//   chunk(row r, kslot q) at byte sub*1024 + q*256 + r*16, staged by gl2lds
//   with pre-swizzled source (row=lane&15, kchunk=lane>>4); linear LDS dest;
//   fragment read = contiguous 16B*lane -> conflict-free.
// Pipeline: 3 rotating slots, depth-2 prefetch, counted vmcnt(S=TM/64+2)
// per step (vmcnt(0) only on the final step), one raw s_barrier per K-step,
// STAGE(t+2) issued between ds_reads and MFMA. Slot-reuse safety as R10/R12.
// ---------------------------------------------------------------------------
template <int ACT, int ORDER, int TM>
__global__ __launch_bounds__(256) void gemm_bt(
    const u16* __restrict__ A,
    const u16* W0, const u16* W1, const u16* W2,
    const float* b0, const float* b1, const float* b2,
    u16* C0, u16* C1, u16* C2,
    int M, int N, int K) {
  constexpr int MI = TM / 32;            // A-frags per wave
  constexpr int S  = TM / 64 + 2;        // gl2lds issues per wave per step
  __shared__ u16 As[3][TM * 32];
  __shared__ u16 Bs[3][128 * 32];
  const int nblk = N >> 7;
  const int mpx = (M / TM) >> 3;         // M-panels per XCD
  const int J = (int)gridDim.x >> 3;
  const int NXB = J / mpx;               // n-blocks total (all mats)
  const int o = (int)blockIdx.x;
  const int xcd = o & 7, j = o >> 3;
  int lp, n;
  if (ORDER == 0) { lp = j / NXB; n = j - lp * NXB; }
  else            { n = j / mpx;  lp = j - n * mpx; }
  const int bm = (xcd * mpx + lp) * TM;
  const int mat = n / nblk;
  const int bn = (n - mat * nblk) << 7;
  const u16* W = mat == 0 ? W0 : (mat == 1 ? W1 : W2);
  const float* bias = mat == 0 ? b0 : (mat == 1 ? b1 : b2);
  u16* C = mat == 0 ? C0 : (mat == 1 ? C1 : C2);

  const int tid  = threadIdx.x;
  const int wave = tid >> 6;
  const int lane = tid & 63;
  const int wrq = wave >> 1, wcq = wave & 1;
  const int r16 = lane & 15, quad = lane >> 4;

  const int nk = K >> 5;

  f32x4 acc[MI][4] = {};

  // stage K-step t into slot s (source pre-swizzled for chunked layout)
  auto STAGE = [&](int s, int t) {
    const int k0 = t << 5;
    #pragma unroll
    for (int q = 0; q < TM / 64; ++q) {
      const int sub = wave * (TM / 64) + q;   // A subtile (16 rows each)
      gl2lds16(A + (size_t)(bm + sub * 16 + r16) * K + (k0 + (quad << 3)),
               (char*)&As[s][0] + (sub << 10));
    }
    #pragma unroll
    for (int q = 0; q < 2; ++q) {
      const int sub = wave * 2 + q;           // B subtile 0..7
      gl2lds16(W + (size_t)(bn + sub * 16 + r16) * K + (k0 + (quad << 3)),
               (char*)&Bs[s][0] + (sub << 10));
    }
  };

  STAGE(0, 0);
  STAGE(1, 1);

  for (int t = 0; t < nk; ++t) {
    const int s = t % 3;
    if (t + 1 < nk) wait_vmcnt<S>(); else wait_vmcnt<0>();
    __builtin_amdgcn_s_barrier();
    __builtin_amdgcn_sched_barrier(0);
    bf16x8 af[MI], bf[4];
    #pragma unroll
    for (int i = 0; i < MI; ++i)
      af[i] = *reinterpret_cast<const bf16x8*>(
          &As[s][((wrq * MI + i) << 9) + (quad << 7) + (r16 << 3)]);
    #pragma unroll
    for (int j_ = 0; j_ < 4; ++j_)
      bf[j_] = *reinterpret_cast<const bf16x8*>(
          &Bs[s][((wcq * 4 + j_) << 9) + (quad << 7) + (r16 << 3)]);
    if (t + 2 < nk) STAGE((t + 2) % 3, t + 2);
    __builtin_amdgcn_sched_barrier(0);
    #pragma unroll
    for (int i = 0; i < MI; ++i)
      #pragma unroll
      for (int j_ = 0; j_ < 4; ++j_)
        acc[i][j_] = __builtin_amdgcn_mfma_f32_16x16x32_bf16(af[i], bf[j_], acc[i][j_], 0, 0, 0);
  }

  #pragma unroll
  for (int j_ = 0; j_ < 4; ++j_) {
    const int nn = bn + wcq * 64 + j_ * 16 + r16;
    const float bv = bias[nn];
    #pragma unroll
    for (int i = 0; i < MI; ++i) {
      const int m0 = bm + wrq * (TM / 2) + i * 16 + quad * 4;
      #pragma unroll
      for (int r = 0; r < 4; ++r) {
        float vv = acc[i][j_][r] + bv;
        if (ACT == 1) vv = fmaxf(vv, 0.0f);
        C[(size_t)(m0 + r) * N + nn] = f2b(vv);
      }
    }
  }
}

// x[b,l,.] = emb[src] + pos_table  -> fp32 nodes + bf16 shadow
__global__ __launch_bounds__(256) void embed_k(
    const int* __restrict__ src, const float* __restrict__ emb,
    const float* __restrict__ pt, float* __restrict__ x,
    u16* __restrict__ xb) {
  const int r = blockIdx.x;
  const int l = r & (SEQ - 1);
  const int tid = threadIdx.x;
  #pragma unroll
  for (int it = 0; it < 3; ++it) {
    const int idx = tid + it * 256;
    const int c = idx >> 8, d = idx & 255;
    const int tok = src[r * 3 + c];
    const float v = emb[(size_t)tok * 256 + d] + pt[(size_t)l * HDIM + idx];
    x[(size_t)r * HDIM + idx] = v;
    xb[(size_t)r * HDIM + idx] = f2b(v);
  }
}

// two-stage relay mean
__global__ __launch_bounds__(256) void relay_mean1_k(
    const float* __restrict__ x, float* __restrict__ part) {
  const int cg = blockIdx.x, seg = blockIdx.y, b = blockIdx.z;
  const int h = cg * 256 + threadIdx.x;
  float s = 0.f;
  const int l0 = seg * 64;
  for (int l = l0; l < l0 + 64; ++l) s += x[((size_t)b * SEQ + l) * HDIM + h];
  part[((size_t)b * 16 + seg) * HDIM + h] = s;
}
__global__ __launch_bounds__(256) void relay_mean2_k(
    const float* __restrict__ part, float* __restrict__ relay) {
  const int b = blockIdx.y;
  const int h = blockIdx.x * 256 + threadIdx.x;
  float s = 0.f;
  #pragma unroll
  for (int i = 0; i < 16; ++i) s += part[((size_t)b * 16 + i) * HDIM + h];
  relay[b * HDIM + h] = s * (1.0f / 1024.0f);
}

// h(bf16) = LN(pre(b16) + res(f32)) * g + b
__global__ __launch_bounds__(256) void ln_resid_k(
    const u16* __restrict__ pre, const float* __restrict__ res,
    const float* __restrict__ g, const float* __restrict__ bb,
    u16* __restrict__ out) {
  __shared__ float red[4];
  const int r = blockIdx.x;
  const int tid = threadIdx.x;
  const size_t base = (size_t)r * HDIM;
  float v0 = b2f(pre[base + tid])       + res[base + tid];
  float v1 = b2f(pre[base + tid + 256]) + res[base + tid + 256];
  float v2 = b2f(pre[base + tid + 512]) + res[base + tid + 512];
  const float mu = blk_sum(v0 + v1 + v2, red) * (1.0f / 768.0f);
  v0 -= mu; v1 -= mu; v2 -= mu;
  const float var = blk_sum(v0 * v0 + v1 * v1 + v2 * v2, red) * (1.0f / 768.0f);
  const float rs = rsqrtf(var + 1e-5f);
  out[base + tid]       = f2b(v0 * rs * g[tid]       + bb[tid]);
  out[base + tid + 256] = f2b(v1 * rs * g[tid + 256] + bb[tid + 256]);
  out[base + tid + 512] = f2b(v2 * rs * g[tid + 512] + bb[tid + 512]);
}

// nodes = mask ? 0 : leaky(LN(pre b16)*g + b)  -> fp32 + bf16 shadow
__global__ __launch_bounds__(256) void ln_leaky_mask_k(
    const u16* __restrict__ pre, const float* __restrict__ g,
    const float* __restrict__ bb, const int* __restrict__ src,
    float* __restrict__ out, u16* __restrict__ outb) {
  __shared__ float red[4];
  const int r = blockIdx.x;
  const int tid = threadIdx.x;
  const size_t base = (size_t)r * HDIM;
  float v0 = b2f(pre[base + tid]);
  float v1 = b2f(pre[base + tid + 256]);
  float v2 = b2f(pre[base + tid + 512]);
  const float mu = blk_sum(v0 + v1 + v2, red) * (1.0f / 768.0f);
  v0 -= mu; v1 -= mu; v2 -= mu;
  const float var = blk_sum(v0 * v0 + v1 * v1 + v2 * v2, red) * (1.0f / 768.0f);
  const float rs = rsqrtf(var + 1e-5f);
  const bool masked = (src[r * 3] == 0);
  float y0 = v0 * rs * g[tid]       + bb[tid];
  float y1 = v1 * rs * g[tid + 256] + bb[tid + 256];
  float y2 = v2 * rs * g[tid + 512] + bb[tid + 512];
  y0 = y0 > 0.f ? y0 : 0.01f * y0;
  y1 = y1 > 0.f ? y1 : 0.01f * y1;
  y2 = y2 > 0.f ? y2 : 0.01f * y2;
  if (masked) { y0 = 0.f; y1 = 0.f; y2 = 0.f; }
  out[base + tid]       = y0;  outb[base + tid]       = f2b(y0);
  out[base + tid + 256] = y1;  outb[base + tid + 256] = f2b(y1);
  out[base + tid + 512] = y2;  outb[base + tid + 512] = f2b(y2);
}

// Ring attention: per (b,l), 4 keys {l-1, l, l+1, relay}.
__global__ __launch_bounds__(256) void ring_attn_k(
    const u16* __restrict__ q, const u16* __restrict__ k,
    const u16* __restrict__ v, const float* __restrict__ rk,
    const float* __restrict__ rv, u16* __restrict__ att) {
  __shared__ float qs[HDIM];
  __shared__ float aw[NHEAD][4];
  const int r = blockIdx.x;
  const int b = r >> 10, l = r & (SEQ - 1);
  const int tid = threadIdx.x;
  const size_t base = (size_t)r * HDIM;
  #pragma unroll
  for (int it = 0; it < 3; ++it) {
    const int idx = tid + it * 256;
    qs[idx] = b2f(q[base + idx]);
  }
  __syncthreads();
  if (tid < 192) {
    const int u_ = tid >> 2;        // 0..47 = (head, window)
    const int l4 = tid & 3;         // 4 lanes, 16 dims each
    const int n = u_ >> 2, w = u_ & 3;
    const float* qrow = qs + n * HD + l4 * 16;
    float a = 0.f;
    if (w < 3) {
      const int ll = l - 1 + w;
      if (ll >= 0 && ll < SEQ) {
        const uint4* kp4 =
            (const uint4*)(k + base + (size_t)(w - 1) * HDIM + n * HD + l4 * 16);
        #pragma unroll
        for (int t = 0; t < 2; ++t) {
          const uint4 u = kp4[t];
          const float2 f0 = b2f2(u.x), f1 = b2f2(u.y);
          const float2 f2_ = b2f2(u.z), f3 = b2f2(u.w);
          const float* q8 = qrow + t * 8;
          a += q8[0] * f0.x + q8[1] * f0.y + q8[2] * f1.x + q8[3] * f1.y
             + q8[4] * f2_.x + q8[5] * f2_.y + q8[6] * f3.x + q8[7] * f3.y;
        }
      }
    } else {
      const float4* kp4 = (const float4*)(rk + b * HDIM + n * HD + l4 * 16);
      #pragma unroll
      for (int t = 0; t < 4; ++t) {
        const float4 kv = kp4[t];
        const float* q4 = qrow + t * 4;
        a += q4[0] * kv.x + q4[1] * kv.y + q4[2] * kv.z + q4[3] * kv.w;
      }
    }
    a += __shfl_xor(a, 1, 4);
    a += __shfl_xor(a, 2, 4);
    if (l4 == 0) aw[n][w] = a * ATT_SCALE;
  }
  __syncthreads();
  if (tid < NHEAD) {
    const float s0 = aw[tid][0], s1 = aw[tid][1], s2 = aw[tid][2], s3 = aw[tid][3];
    const float m = fmaxf(fmaxf(s0, s1), fmaxf(s2, s3));
    const float e0 = __expf(s0 - m), e1 = __expf(s1 - m);
    const float e2 = __expf(s2 - m), e3 = __expf(s3 - m);
    const float inv = 1.0f / (e0 + e1 + e2 + e3);
    aw[tid][0] = e0 * inv; aw[tid][1] = e1 * inv;
    aw[tid][2] = e2 * inv; aw[tid][3] = e3 * inv;
  }
  __syncthreads();
  #pragma unroll
  for (int it = 0; it < 3; ++it) {
    const int idx = tid + it * 256;
    const int n = idx >> 6;
    float acc = aw[n][3] * rv[b * HDIM + idx];
    if (l > 0)       acc += aw[n][0] * b2f(v[base - HDIM + idx]);
    acc += aw[n][1] * b2f(v[base + idx]);
    if (l < SEQ - 1) acc += aw[n][2] * b2f(v[base + HDIM + idx]);
    att[base + idx] = f2b(acc);
  }
}

// Star (relay) attention: per (b,head) block; 1025 keys = [relay; nodes].
__global__ __launch_bounds__(256) void msa2_attn_k(
    const float* __restrict__ q2, const float* __restrict__ rk2,
    const float* __restrict__ rv2, const u16* __restrict__ k2,
    const u16* __restrict__ v2, const int* __restrict__ src,
    float* __restrict__ att) {
  __shared__ float qs[HD];
  __shared__ float sc[SEQ + 1];
  __shared__ float red[4];
  __shared__ float vred[4][HD];
  const int bid = blockIdx.x;
  const int b = bid / NHEAD, n = bid % NHEAD;
  const int tid = threadIdx.x;
  const int hb = b * HDIM + n * HD;
  if (tid < HD) qs[tid] = q2[hb + tid];
  __syncthreads();
  float lmax = -1e30f;
  for (int s = tid; s <= SEQ; s += 256) {
    float sco;
    if (s == 0) {
      float a = 0.f;
      #pragma unroll
      for (int d = 0; d < HD; ++d) a += qs[d] * rk2[hb + d];
      sco = a * ATT_SCALE;
    } else {
      const int l = s - 1;
      if (src[(b * SEQ + l) * 3] == 0) {
        sco = -1e30f;
      } else {
        const uint4* kp4 =
            (const uint4*)(k2 + ((size_t)b * SEQ + l) * HDIM + n * HD);
        float a = 0.f;
        #pragma unroll
        for (int t = 0; t < 8; ++t) {
          const uint4 u = kp4[t];
          const float2 f0 = b2f2(u.x), f1 = b2f2(u.y);
          const float2 f2_ = b2f2(u.z), f3 = b2f2(u.w);
          const float* q8 = qs + t * 8;
          a += q8[0] * f0.x + q8[1] * f0.y + q8[2] * f1.x + q8[3] * f1.y
             + q8[4] * f2_.x + q8[5] * f2_.y + q8[6] * f3.x + q8[7] * f3.y;
        }
        sco = a * ATT_SCALE;
      }
    }
    sc[s] = sco;
    lmax = fmaxf(lmax, sco);
  }
  lmax = blk_max(lmax, red);
  float lsum = 0.f;
  for (int s = tid; s <= SEQ; s += 256) {
    const float e = __expf(sc[s] - lmax);
    sc[s] = e;
    lsum += e;
  }
  lsum = blk_sum(lsum, red);   // syncs; sc[] fully written after this
  {
    const int dd = tid & 63, grp = tid >> 6;
    float acc = 0.f;
    const u16* vp = v2 + (size_t)b * SEQ * HDIM + n * HD + dd;
    for (int l = grp; l < SEQ; l += 4)
      acc += sc[l + 1] * b2f(vp[(size_t)l * HDIM]);
    vred[grp][dd] = acc;
  }
  __syncthreads();
  if (tid < HD) {
    const float inv = 1.0f / lsum;
    const float a = sc[0] * rv2[hb + tid]
                  + vred[0][tid] + vred[1][tid] + vred[2][tid] + vred[3][tid];
    att[hb + tid] = a * inv;
  }
}

// Relay projections: one wave per (mat, n) WEIGHT ROW; accumulate 8 batches.
__global__ __launch_bounds__(256) void relay_proj_k(
    const float* __restrict__ A, int N, int nm,
    const float* W0, const float* W1, const float* W2,
    const float* b0, const float* b1, const float* b2v,
    float* O0, float* O1, float* O2, int act) {
  const int wid = blockIdx.x * 4 + (threadIdx.x >> 6);
  const int lane = threadIdx.x & 63;
  const int mat = wid / N, n = wid % N;
  const float* W  = mat == 0 ? W0 : (mat == 1 ? W1 : W2);
  const float* bb = mat == 0 ? b0 : (mat == 1 ? b1 : b2v);
  float* O        = mat == 0 ? O0 : (mat == 1 ? O1 : O2);
  const float4* wr = (const float4*)(W + (size_t)n * HDIM);
  float acc[NB] = {};
  #pragma unroll
  for (int it = 0; it < 3; ++it) {
    const int k4 = it * 64 + lane;
    const float4 wv = wr[k4];
    #pragma unroll
    for (int b = 0; b < NB; ++b) {
      const float4 av = *(const float4*)&A[b * HDIM + k4 * 4];
      acc[b] += av.x * wv.x + av.y * wv.y + av.z * wv.z + av.w * wv.w;
    }
  }
  #pragma unroll
  for (int b = 0; b < NB; ++b) {
    float a = acc[b];
    #pragma unroll
    for (int off = 32; off > 0; off >>= 1) a += __shfl_down(a, off, 64);
    if (lane == 0) {
      float v = a + bb[n];
      if (act == 2) v = v > 0.f ? v : 0.01f * v;
      O[(size_t)b * N + n] = v;
    }
  }
}

// ft[b] = [relay[b] ; nodes[b, positions[b]]]
__global__ __launch_bounds__(256) void ft_k(
    const float* __restrict__ relay, const float* __restrict__ nodes,
    const int* __restrict__ positions, float* __restrict__ ft) {
  const int gid = blockIdx.x * 256 + threadIdx.x;
  const int b = gid / 1536, j = gid % 1536;
  if (j < HDIM) {
    ft[gid] = relay[b * HDIM + j];
  } else {
    const int p = positions[b];
    ft[gid] = nodes[((size_t)b * SEQ + p) * HDIM + (j - HDIM)];
  }
}

// head1: one wave per (j,o) weight row; ft (8x1536 = 48 KB) in LDS.
__global__ __launch_bounds__(256) void head1_k(
    const float* __restrict__ ft, const float* __restrict__ w,
    const float* __restrict__ bias, float* __restrict__ hid) {
  __shared__ float fs[NB * 1536];
  const int j = blockIdx.y;
  {
    const float4* s4 = (const float4*)ft;
    float4* d4 = (float4*)fs;
    for (int i = threadIdx.x; i < (NB * 1536) / 4; i += 256) d4[i] = s4[i];
  }
  __syncthreads();
  const int wave = threadIdx.x >> 6, lane = threadIdx.x & 63;
  const int o = blockIdx.x * 4 + wave;
  const float4* wr = (const float4*)(w + ((size_t)j * NHID + o) * 1536);
  float acc[NB] = {};
  #pragma unroll
  for (int it = 0; it < 6; ++it) {
    const int k4 = it * 64 + lane;
    const float4 wv = wr[k4];
    #pragma unroll
    for (int b = 0; b < NB; ++b) {
      const float4 hv = *(const float4*)&fs[b * 1536 + k4 * 4];
      acc[b] += hv.x * wv.x + hv.y * wv.y + hv.z * wv.z + hv.w * wv.w;
    }
  }
  #pragma unroll
  for (int b = 0; b < NB; ++b) {
    float a = acc[b];
    #pragma unroll
    for (int off = 32; off > 0; off >>= 1) a += __shfl_down(a, off, 64);
    if (lane == 0)
      hid[((size_t)j * NB + b) * NHID + o] = fmaxf(a + bias[j * NHID + o], 0.f);
  }
}

// head2: one wave per (j,o) weight row; hid[j] (8x1024 = 32 KB) in LDS.
__global__ __launch_bounds__(256) void head2_k(
    const float* __restrict__ hid, const float* __restrict__ w,
    const float* __restrict__ bias, float* __restrict__ out) {
  __shared__ float hs[NB * NHID];
  const int j = blockIdx.y;
  {
    const float4* s4 = (const float4*)(hid + (size_t)j * NB * NHID);
    float4* d4 = (float4*)hs;
    for (int i = threadIdx.x; i < (NB * NHID) / 4; i += 256) d4[i] = s4[i];
  }
  __syncthreads();
  const int wave = threadIdx.x >> 6, lane = threadIdx.x & 63;
  const int o = blockIdx.x * 4 + wave;
  const float4* wr = (const float4*)(w + ((size_t)j * NOUT + o) * NHID);
  float acc[NB] = {};
  #pragma unroll
  for (int it = 0; it < 4; ++it) {
    const int k4 = it * 64 + lane;
    const float4 wv = wr[k4];
    #pragma unroll
    for (int b = 0; b < NB; ++b) {
      const float4 hv = *(const float4*)&hs[b * NHID + k4 * 4];
      acc[b] += hv.x * wv.x + hv.y * wv.y + hv.z * wv.z + hv.w * wv.w;
    }
  }
  #pragma unroll
  for (int b = 0; b < NB; ++b) {
    float a = acc[b];
    #pragma unroll
    for (int off = 32; off > 0; off >>= 1) a += __shfl_down(a, off, 64);
    if (lane == 0)
      out[(size_t)(b * 3 + j) * NOUT + o] = a + bias[j * NOUT + o];
  }
}

// ---------------------------------------------------------------------------
extern "C" void kernel_launch(void* const* d_in, const int* in_sizes, int n_in,
                              void* d_out, int out_size, void* d_ws, size_t ws_size,
                              hipStream_t stream) {
  (void)in_sizes; (void)n_in; (void)out_size; (void)ws_size;
  const int* src       = (const int*)d_in[0];
  const int* positions = (const int*)d_in[1];
  const float* emb   = (const float*)d_in[2];
  const float* pt    = (const float*)d_in[3];
  const float* norm_g = (const float*)d_in[4]; const float* norm_b = (const float*)d_in[5];
  const float* pw_w1 = (const float*)d_in[6];  const float* pw_b1 = (const float*)d_in[7];
  const float* pw_w2 = (const float*)d_in[8];  const float* pw_b2 = (const float*)d_in[9];
  const float* pw_g  = (const float*)d_in[10]; const float* pw_bn = (const float*)d_in[11];
  const float* ring_wq = (const float*)d_in[12]; const float* ring_bq = (const float*)d_in[13];
  const float* ring_wk = (const float*)d_in[14]; const float* ring_bk = (const float*)d_in[15];
  const float* ring_wv = (const float*)d_in[16]; const float* ring_bv = (const float*)d_in[17];
  const float* ring_wo = (const float*)d_in[18]; const float* ring_bo = (const float*)d_in[19];
  const float* star_wq = (const float*)d_in[20]; const float* star_bq = (const float*)d_in[21];
  const float* star_wk = (const float*)d_in[22]; const float* star_bk = (const float*)d_in[23];
  const float* star_wv = (const float*)d_in[24]; const float* star_bv = (const float*)d_in[25];
  const float* star_wo = (const float*)d_in[26]; const float* star_bo = (const float*)d_in[27];
  const float* head_w1 = (const float*)d_in[28]; const float* head_b1 = (const float*)d_in[29];
  const float* head_w2 = (const float*)d_in[30]; const float* head_b2 = (const float*)d_in[31];

  // ---------------- workspace: 8 units of NTOK*2 bytes (12.58 MB) ----------
  char* ws = (char*)d_ws;
  const size_t NTOK = (size_t)NB * SEQ * HDIM;            // 6,291,456 elems
  const size_t U = NTOK * 2;                              // unit = 12,582,912 B
  float* nodes   = (float*)(ws);                          // U0,U1 (fp32)
  u16* inner     = (u16*)(ws + 2 * U);                    // U2..U5 [M][3072]
  u16* prelnA    = (u16*)(ws + 6 * U);                    // U6
  u16* hbuf      = (u16*)(ws + 2 * U);                    // U2
  u16* qb        = (u16*)(ws + 3 * U);                    // U3
  u16* kb        = (u16*)(ws + 4 * U);                    // U4
  u16* vb        = (u16*)(ws + 5 * U);                    // U5
  u16* attb      = (u16*)(ws + 6 * U);                    // U6 (prelnA dead)
  u16* prelnB    = (u16*)(ws + 3 * U);                    // U3 (qb dead)
  u16* nodes_b16 = (u16*)(ws + 7 * U);                    // U7
  u16* k2b       = (u16*)(ws + 4 * U);                    // U4 (phase C)
  u16* v2b       = (u16*)(ws + 5 * U);                    // U5 (phase C)
  u16* wc        = (u16*)(ws + 8 * U);                    // 9,437,184 B weight-cvt
  char* small    = ws + 8 * U + 9437184;
  float* part  = (float*)(small);                          // 393,216
  float* relay = (float*)(small + 393216);
  float* sb0 = (float*)(small + 393216 + 1 * 24576);
  float* sb1 = (float*)(small + 393216 + 2 * 24576);
  float* sb2 = (float*)(small + 393216 + 3 * 24576);
  float* sb3 = (float*)(small + 393216 + 4 * 24576);
  float* ftb = (float*)(small + 393216 + 5 * 24576);
  float* hid = (float*)(small + 393216 + 5 * 24576 + 49152);

  embed_k<<<NB * SEQ, 256, 0, stream>>>(src, emb, pt, nodes, nodes_b16);
  relay_mean1_k<<<dim3(3, 16, NB), 256, 0, stream>>>(nodes, part);
  relay_mean2_k<<<dim3(3, NB), 256, 0, stream>>>(part, relay);

  const int NW1 = DINNER * HDIM;   // 2,359,296 elems per layer slice
  const int NQK = HDIM * HDIM;     // 589,824
  const int M = NB * SEQ;          // 8192

  for (int i = 0; i < 2; ++i) {
    const float* pw_w1_l = pw_w1 + (size_t)i * NW1;
    const float* pw_w2_l = pw_w2 + (size_t)i * NW1;
    const float* pw_b1_l = pw_b1 + (size_t)i * DINNER;
    const float* pw_b2_l = pw_b2 + (size_t)i * HDIM;
    const float* pw_g_l  = pw_g + (size_t)i * HDIM;
    const float* pw_bn_l = pw_bn + (size_t)i * HDIM;
    const float* ng_l = norm_g + (size_t)i * HDIM;
    const float* nb_l = norm_b + (size_t)i * HDIM;
    const float* rwq = ring_wq + (size_t)i * NQK; const float* rbq = ring_bq + (size_t)i * HDIM;
    const float* rwk = ring_wk + (size_t)i * NQK; const float* rbk = ring_bk + (size_t)i * HDIM;
    const float* rwv = ring_wv + (size_t)i * NQK; const float* rbv = ring_bv + (size_t)i * HDIM;
    const float* rwo = ring_wo + (size_t)i * NQK; const float* rbo = ring_bo + (size_t)i * HDIM;
    const float* swq = star_wq + (size_t)i * NQK; const float* sbq = star_bq + (size_t)i * HDIM;
    const float* swk = star_wk + (size_t)i * NQK; const float* sbk = star_bk + (size_t)i * HDIM;
    const float* swv = star_wv + (size_t)i * NQK; const float* sbv = star_bv + (size_t)i * HDIM;
    const float* swo = star_wo + (size_t)i * NQK; const float* sbo = star_bo + (size_t)i * HDIM;

    // ---- phase A: FFN ----
    u16* wc_pw1 = wc;
    u16* wc_pw2 = wc + NW1;
    {
      Cvt4 a = { pw_w1_l, pw_w2_l, pw_w1_l, pw_w1_l,
                 wc_pw1, wc_pw2, wc_pw1, wc_pw1,
                 NW1 / 4, NW1 / 2, NW1 / 2, NW1 / 2 };
      cvt4_k<<<(NW1 / 2 + 255) / 256, 256, 0, stream>>>(a);
    }
    // pw_w1: N=3072, TM=128 -> grid 1536 = 6/CU; ORDER=1 (W-block resident)
    gemm_bt<1, 1, 128><<<(DINNER / 128) * (M / 128), 256, 0, stream>>>(
        nodes_b16, wc_pw1, wc_pw1, wc_pw1, pw_b1_l, pw_b1_l, pw_b1_l,
        inner, inner, inner, M, DINNER, HDIM);
    // pw_w2: TM=64 -> grid 768 = 3/CU; ORDER=0 (A-panel resident)
    gemm_bt<0, 0, 64><<<(HDIM / 128) * (M / 64), 256, 0, stream>>>(
        inner, wc_pw2, wc_pw2, wc_pw2, pw_b2_l, pw_b2_l, pw_b2_l,
        prelnA, prelnA, prelnA, M, HDIM, DINNER);
    // inner dead; hbuf=U2 safe to write.
    ln_resid_k<<<M, 256, 0, stream>>>(prelnA, nodes, pw_g_l, pw_bn_l, hbuf);

    // ---- phase B: ring attention ----
    u16* wc_rq = wc;
    u16* wc_rk = wc + NQK;
    u16* wc_rv = wc + 2 * NQK;
    u16* wc_ro = wc + 3 * NQK;
    {
      Cvt4 a = { rwq, rwk, rwv, rwo, wc_rq, wc_rk, wc_rv, wc_ro,
                 NQK / 4, NQK / 2, 3 * NQK / 4, NQK };
      cvt4_k<<<(NQK + 255) / 256, 256, 0, stream>>>(a);
    }
    // fused q,k,v: TM=64 -> grid 2304 = 9/CU; ORDER=0
    gemm_bt<0, 0, 64><<<3 * (HDIM / 128) * (M / 64), 256, 0, stream>>>(
        hbuf, wc_rq, wc_rk, wc_rv, rbq, rbk, rbv,
        qb, kb, vb, M, HDIM, HDIM);
    relay_proj_k<<<2 * HDIM / 4, 256, 0, stream>>>(
        relay, HDIM, 2, rwk, rwv, rwk, rbk, rbv, rbk, sb0, sb1, sb2, 0);
    ring_attn_k<<<NB * SEQ, 256, 0, stream>>>(qb, kb, vb, sb0, sb1, attb);
    // qb(U3) dead -> prelnB
    gemm_bt<0, 0, 64><<<(HDIM / 128) * (M / 64), 256, 0, stream>>>(
        attb, wc_ro, wc_ro, wc_ro, rbo, rbo, rbo,
        prelnB, prelnB, prelnB, M, HDIM, HDIM);
    ln_leaky_mask_k<<<M, 256, 0, stream>>>(prelnB, ng_l, nb_l, src, nodes, nodes_b16);

    // ---- phase C: star attention ----
    u16* wc_sk = wc;
    u16* wc_sv = wc + NQK;
    {
      Cvt4 a = { swk, swv, swk, swk, wc_sk, wc_sv, wc_sk, wc_sk,
                 NQK / 4, NQK / 2, NQK / 2, NQK / 2 };
      cvt4_k<<<(NQK / 2 + 255) / 256, 256, 0, stream>>>(a);
    }
    // fused k2,v2: TM=64 -> grid 1536 = 6/CU; ORDER=0
    gemm_bt<0, 0, 64><<<2 * (HDIM / 128) * (M / 64), 256, 0, stream>>>(
        nodes_b16, wc_sk, wc_sv, wc_sv, sbk, sbv, sbv,
        k2b, v2b, v2b, M, HDIM, HDIM);
    relay_proj_k<<<3 * HDIM / 4, 256, 0, stream>>>(
        relay, HDIM, 3, swq, swk, swv, sbq, sbk, sbv, sb0, sb1, sb2, 0);
    msa2_attn_k<<<NB * NHEAD, 256, 0, stream>>>(sb0, sb1, sb2, k2b, v2b, src, sb3);
    relay_proj_k<<<HDIM / 4, 256, 0, stream>>>(
        sb3, HDIM, 1, swo, swo, swo, sbo, sbo, sbo, relay, sb1, sb2, 2);
  }

  ft_k<<<48, 256, 0, stream>>>(relay, nodes, positions, ftb);
  head1_k<<<dim3(NHID / 4, 3), 256, 0, stream>>>(ftb, head_w1, head_b1, hid);
  head2_k<<<dim3(NOUT / 4, 3), 256, 0, stream>>>(hid, head_w2, head_b2, (float*)d_out);
}

// Round 9
// 1058.843 us; speedup vs baseline: 1.1699x; 1.1699x over previous
//
#include <hip/hip_runtime.h>
#include <cstdint>
#include <cstddef>

// ---------------------------------------------------------------------------
// Star-Transformer forward on MI355X. R15 = R14 resubmitted verbatim (R8's
// bench was an infra failure: "MI355X container failed twice" — no data).
// Ledger: R0 (TM=128 simple GEMM + R0 attn) = 1042us. R7 bundled {TM=64 GEMM
// (measured -3us/dispatch)} + {attn rewrite (never isolated)} = 1090us
// => attn rewrite ~= +50-60us regression, carried ever since. R12/R13 swizzle:
// fetch 157->43MB but time 83->96->112us (latency-serialized) => dropped.
// This round keeps ONLY proven-per-dispatch wins:
//  - gemm_bt = R8 version verbatim (TM=64 4-slot rotating LDS, counted vmcnt,
//    one barrier/K-step; TM=128 for pw_w1; z-fused qkv / star-kv; measured
//    83.3us pw_w2-class vs R0's 89.0).
//  - ring_attn_k / msa2_attn_k = R0 versions verbatim.
//  - 8-unit workspace liveness layout (passed R11/R13).
// ---------------------------------------------------------------------------

typedef unsigned short u16;
typedef __attribute__((ext_vector_type(4))) float f32x4;
typedef __attribute__((ext_vector_type(8))) __bf16 bf16x8;

#define NB 8
#define SEQ 1024
#define HDIM 768
#define NHEAD 12
#define HD 64
#define DINNER 3072
#define NHID 1024
#define NOUT 5000
#define ATT_SCALE 0.125f

static __device__ __forceinline__ float b2f(u16 u) {
  union { float f; uint32_t i; } v; v.i = ((uint32_t)u) << 16; return v.f;
}
static __device__ __forceinline__ u16 f2b(float f) {
  union { float f; uint32_t i; } v; v.f = f;
  uint32_t r = v.i + 0x7fffu + ((v.i >> 16) & 1u);
  return (u16)(r >> 16);
}

// async global->LDS, 16B per lane; LDS dest = wave-uniform base + lane*16.
static __device__ __forceinline__ void gl2lds16(const void* g, void* l) {
  __builtin_amdgcn_global_load_lds(
      (__attribute__((address_space(1))) void*)(uintptr_t)g,
      (__attribute__((address_space(3))) void*)l, 16, 0, 0);
}

template <int N>
static __device__ __forceinline__ void wait_vmcnt() {
  if constexpr (N == 0) asm volatile("s_waitcnt vmcnt(0)" ::: "memory");
  else if constexpr (N == 3) asm volatile("s_waitcnt vmcnt(3)" ::: "memory");
  else if constexpr (N == 4) asm volatile("s_waitcnt vmcnt(4)" ::: "memory");
  else if constexpr (N == 6) asm volatile("s_waitcnt vmcnt(6)" ::: "memory");
  else if constexpr (N == 8) asm volatile("s_waitcnt vmcnt(8)" ::: "memory");
}

static __device__ __forceinline__ float blk_sum(float v, float* red) {
  #pragma unroll
  for (int off = 32; off > 0; off >>= 1) v += __shfl_down(v, off, 64);
  if ((threadIdx.x & 63) == 0) red[threadIdx.x >> 6] = v;
  __syncthreads();
  float r = red[0] + red[1] + red[2] + red[3];
  __syncthreads();
  return r;
}
static __device__ __forceinline__ float blk_max(float v, float* red) {
  #pragma unroll
  for (int off = 32; off > 0; off >>= 1) v = fmaxf(v, __shfl_down(v, off, 64));
  if ((threadIdx.x & 63) == 0) red[threadIdx.x >> 6] = v;
  __syncthreads();
  float r = fmaxf(fmaxf(red[0], red[1]), fmaxf(red[2], red[3]));
  __syncthreads();
  return r;
}

// ---------------------------------------------------------------------------
// Segmented fp32 -> bf16 converter (up to 4 tensors per dispatch).
// ---------------------------------------------------------------------------
struct Cvt4 {
  const float* s0; const float* s1; const float* s2; const float* s3;
  u16* d0; u16* d1; u16* d2; u16* d3;
  int c1, c2, c3, c4;
};
__global__ __launch_bounds__(256) void cvt4_k(Cvt4 a) {
  const int i = blockIdx.x * 256 + threadIdx.x;
  if (i >= a.c4) return;
  const float* s; u16* d; int j;
  if (i < a.c1)      { s = a.s0; d = a.d0; j = i; }
  else if (i < a.c2) { s = a.s1; d = a.d1; j = i - a.c1; }
  else if (i < a.c3) { s = a.s2; d = a.d2; j = i - a.c2; }
  else               { s = a.s3; d = a.d3; j = i - a.c3; }
  const float4 v = ((const float4*)s)[j];
  ushort4 o;
  o.x = f2b(v.x); o.y = f2b(v.y); o.z = f2b(v.z); o.w = f2b(v.w);
  ((ushort4*)d)[j] = o;
}

// ---------------------------------------------------------------------------
// NT GEMM (R8 version): C[M,N] = act(A[M,K] . Wz[N,K]^T + biasz[N]).
// Grid: (NMAT * N/128, M/TM); mat = blockIdx.x / (N/128) selects W/bias/C
// (z-fusion). TM x 128 tile, 4 waves (2x2), wave owns (TM/2) x 64,
// mfma_f32_16x16x32_bf16, MI = TM/32 A-frags per wave.
// Pipeline: 4 rotating LDS slots, depth-2 prefetch via global_load_lds,
// per-iter: STAGE(t+2) -> s_waitcnt vmcnt(2S) -> s_barrier -> ds_read + MFMA.
// vmcnt never drains to 0 in the main loop. Slot s staged at iter t is
// re-staged at t+4; readers at iter t consumed before their barrier t+1 and
// the re-stage happens after barrier t+1. Measured: 83.3us pw_w2-class,
// 0.0039 absmax (R8 bench).
// ---------------------------------------------------------------------------
template <int ACT, int TM>
__global__ __launch_bounds__(256) void gemm_bt(
    const u16* __restrict__ A,
    const u16* W0, const u16* W1, const u16* W2,
    const float* b0, const float* b1, const float* b2,
    u16* C0, u16* C1, u16* C2,
    int M, int N, int K) {
  constexpr int MI = TM / 32;           // A-frags per wave
  constexpr int S = TM / 64 + 2;        // gl2lds issues per wave per step
  __shared__ u16 As[4][TM * 32];
  __shared__ u16 Bs[4][128 * 32];
  const int nblk = N >> 7;
  const int mat = (int)blockIdx.x / nblk;
  const u16* W = mat == 0 ? W0 : (mat == 1 ? W1 : W2);
  const float* bias = mat == 0 ? b0 : (mat == 1 ? b1 : b2);
  u16* C = mat == 0 ? C0 : (mat == 1 ? C1 : C2);

  const int tid  = threadIdx.x;
  const int wave = tid >> 6;
  const int lane = tid & 63;
  const int bm = blockIdx.y * TM;
  const int bn = ((int)blockIdx.x - mat * nblk) * 128;
  const int wrq = wave >> 1, wcq = wave & 1;
  const int r16 = lane & 15, quad = lane >> 4;
  const int srow = lane >> 2;        // 0..15
  const int scol = (lane & 3) << 3;  // 0,8,16,24 bf16 elements

  f32x4 acc[MI][4] = {};

  const int nk = K >> 5;

  // stage K-step t into slot s
  auto STAGE = [&](int s, int t) {
    const int k0 = t << 5;
    #pragma unroll
    for (int q = 0; q < TM / 64; ++q) {
      const int rowa = wave * (TM / 4) + q * 16;
      gl2lds16(A + (size_t)(bm + rowa + srow) * K + (k0 + scol),
               (char*)&As[s][0] + (rowa << 6));
    }
    #pragma unroll
    for (int q = 0; q < 2; ++q) {
      const int rowb = wave * 32 + q * 16;
      gl2lds16(W + (size_t)(bn + rowb + srow) * K + (k0 + scol),
               (char*)&Bs[s][0] + (rowb << 6));
    }
  };

  // prologue: prefetch steps 0 and 1
  STAGE(0, 0);
  if (1 < nk) STAGE(1, 1);

  for (int t = 0; t < nk; ++t) {
    const int s = t & 3;
    if (t + 2 < nk) {
      STAGE((t + 2) & 3, t + 2);
      __builtin_amdgcn_sched_barrier(0);
      wait_vmcnt<2 * S>();
    } else if (t + 1 < nk) {
      wait_vmcnt<S>();
    } else {
      wait_vmcnt<0>();
    }
    __builtin_amdgcn_sched_barrier(0);
    __builtin_amdgcn_s_barrier();
    __builtin_amdgcn_sched_barrier(0);

    bf16x8 af[MI], bf[4];
    #pragma unroll
    for (int i = 0; i < MI; ++i)
      af[i] = *reinterpret_cast<const bf16x8*>(
          &As[s][(wrq * (TM / 2) + i * 16 + r16) * 32 + quad * 8]);
    #pragma unroll
    for (int j = 0; j < 4; ++j)
      bf[j] = *reinterpret_cast<const bf16x8*>(
          &Bs[s][(wcq * 64 + j * 16 + r16) * 32 + quad * 8]);
    #pragma unroll
    for (int i = 0; i < MI; ++i)
      #pragma unroll
      for (int j = 0; j < 4; ++j)
        acc[i][j] = __builtin_amdgcn_mfma_f32_16x16x32_bf16(af[i], bf[j], acc[i][j], 0, 0, 0);
  }

  #pragma unroll
  for (int j = 0; j < 4; ++j) {
    const int n = bn + wcq * 64 + j * 16 + r16;
    const float bv = bias[n];
    #pragma unroll
    for (int i = 0; i < MI; ++i) {
      const int m0 = bm + wrq * (TM / 2) + i * 16 + quad * 4;
      #pragma unroll
      for (int r = 0; r < 4; ++r) {
        float vv = acc[i][j][r] + bv;
        if (ACT == 1) vv = fmaxf(vv, 0.0f);
        C[(size_t)(m0 + r) * N + n] = f2b(vv);
      }
    }
  }
}

// x[b,l,.] = emb[src] + pos_table  -> fp32 nodes + bf16 shadow
__global__ __launch_bounds__(256) void embed_k(
    const int* __restrict__ src, const float* __restrict__ emb,
    const float* __restrict__ pt, float* __restrict__ x,
    u16* __restrict__ xb) {
  const int r = blockIdx.x;
  const int l = r & (SEQ - 1);
  const int tid = threadIdx.x;
  #pragma unroll
  for (int it = 0; it < 3; ++it) {
    const int idx = tid + it * 256;
    const int c = idx >> 8, d = idx & 255;
    const int tok = src[r * 3 + c];
    const float v = emb[(size_t)tok * 256 + d] + pt[(size_t)l * HDIM + idx];
    x[(size_t)r * HDIM + idx] = v;
    xb[(size_t)r * HDIM + idx] = f2b(v);
  }
}

// two-stage relay mean
__global__ __launch_bounds__(256) void relay_mean1_k(
    const float* __restrict__ x, float* __restrict__ part) {
  const int cg = blockIdx.x, seg = blockIdx.y, b = blockIdx.z;
  const int h = cg * 256 + threadIdx.x;
  float s = 0.f;
  const int l0 = seg * 64;
  for (int l = l0; l < l0 + 64; ++l) s += x[((size_t)b * SEQ + l) * HDIM + h];
  part[((size_t)b * 16 + seg) * HDIM + h] = s;
}
__global__ __launch_bounds__(256) void relay_mean2_k(
    const float* __restrict__ part, float* __restrict__ relay) {
  const int b = blockIdx.y;
  const int h = blockIdx.x * 256 + threadIdx.x;
  float s = 0.f;
  #pragma unroll
  for (int i = 0; i < 16; ++i) s += part[((size_t)b * 16 + i) * HDIM + h];
  relay[b * HDIM + h] = s * (1.0f / 1024.0f);
}

// h(bf16) = LN(pre(b16) + res(f32)) * g + b
__global__ __launch_bounds__(256) void ln_resid_k(
    const u16* __restrict__ pre, const float* __restrict__ res,
    const float* __restrict__ g, const float* __restrict__ bb,
    u16* __restrict__ out) {
  __shared__ float red[4];
  const int r = blockIdx.x;
  const int tid = threadIdx.x;
  const size_t base = (size_t)r * HDIM;
  float v0 = b2f(pre[base + tid])       + res[base + tid];
  float v1 = b2f(pre[base + tid + 256]) + res[base + tid + 256];
  float v2 = b2f(pre[base + tid + 512]) + res[base + tid + 512];
  const float mu = blk_sum(v0 + v1 + v2, red) * (1.0f / 768.0f);
  v0 -= mu; v1 -= mu; v2 -= mu;
  const float var = blk_sum(v0 * v0 + v1 * v1 + v2 * v2, red) * (1.0f / 768.0f);
  const float rs = rsqrtf(var + 1e-5f);
  out[base + tid]       = f2b(v0 * rs * g[tid]       + bb[tid]);
  out[base + tid + 256] = f2b(v1 * rs * g[tid + 256] + bb[tid + 256]);
  out[base + tid + 512] = f2b(v2 * rs * g[tid + 512] + bb[tid + 512]);
}

// nodes = mask ? 0 : leaky(LN(pre)*g + b)  -> fp32 + bf16 shadow
__global__ __launch_bounds__(256) void ln_leaky_mask_k(
    const u16* __restrict__ pre, const float* __restrict__ g,
    const float* __restrict__ bb, const int* __restrict__ src,
    float* __restrict__ out, u16* __restrict__ outb) {
  __shared__ float red[4];
  const int r = blockIdx.x;
  const int tid = threadIdx.x;
  const size_t base = (size_t)r * HDIM;
  float v0 = b2f(pre[base + tid]);
  float v1 = b2f(pre[base + tid + 256]);
  float v2 = b2f(pre[base + tid + 512]);
  const float mu = blk_sum(v0 + v1 + v2, red) * (1.0f / 768.0f);
  v0 -= mu; v1 -= mu; v2 -= mu;
  const float var = blk_sum(v0 * v0 + v1 * v1 + v2 * v2, red) * (1.0f / 768.0f);
  const float rs = rsqrtf(var + 1e-5f);
  const bool masked = (src[r * 3] == 0);
  float y0 = v0 * rs * g[tid]       + bb[tid];
  float y1 = v1 * rs * g[tid + 256] + bb[tid + 256];
  float y2 = v2 * rs * g[tid + 512] + bb[tid + 512];
  y0 = y0 > 0.f ? y0 : 0.01f * y0;
  y1 = y1 > 0.f ? y1 : 0.01f * y1;
  y2 = y2 > 0.f ? y2 : 0.01f * y2;
  if (masked) { y0 = 0.f; y1 = 0.f; y2 = 0.f; }
  out[base + tid]       = y0;  outb[base + tid]       = f2b(y0);
  out[base + tid + 256] = y1;  outb[base + tid + 256] = f2b(y1);
  out[base + tid + 512] = y2;  outb[base + tid + 512] = f2b(y2);
}

// Ring attention (R0 version): per (b,l), 4 keys {l-1, l, l+1, relay}.
__global__ __launch_bounds__(256) void ring_attn_k(
    const u16* __restrict__ q, const u16* __restrict__ k,
    const u16* __restrict__ v, const float* __restrict__ rk,
    const float* __restrict__ rv, u16* __restrict__ att) {
  __shared__ float qs[HDIM];
  __shared__ float aw[NHEAD][4];
  const int r = blockIdx.x;
  const int b = r >> 10, l = r & (SEQ - 1);
  const int tid = threadIdx.x;
  const size_t base = (size_t)r * HDIM;
  #pragma unroll
  for (int it = 0; it < 3; ++it) {
    const int idx = tid + it * 256;
    qs[idx] = b2f(q[base + idx]);
  }
  __syncthreads();
  if (tid < NHEAD * 4) {
    const int n = tid >> 2, w = tid & 3;
    float a = 0.f;
    if (w < 3) {
      const int ll = l - 1 + w;
      if (ll >= 0 && ll < SEQ) {
        const u16* kp = k + base + (size_t)(w - 1) * HDIM + n * HD;
        #pragma unroll
        for (int d = 0; d < HD; ++d) a += qs[n * HD + d] * b2f(kp[d]);
      }
    } else {
      const float* kp = rk + b * HDIM + n * HD;
      #pragma unroll
      for (int d = 0; d < HD; ++d) a += qs[n * HD + d] * kp[d];
    }
    aw[n][w] = a * ATT_SCALE;
  }
  __syncthreads();
  if (tid < NHEAD) {
    const float s0 = aw[tid][0], s1 = aw[tid][1], s2 = aw[tid][2], s3 = aw[tid][3];
    const float m = fmaxf(fmaxf(s0, s1), fmaxf(s2, s3));
    const float e0 = __expf(s0 - m), e1 = __expf(s1 - m);
    const float e2 = __expf(s2 - m), e3 = __expf(s3 - m);
    const float inv = 1.0f / (e0 + e1 + e2 + e3);
    aw[tid][0] = e0 * inv; aw[tid][1] = e1 * inv;
    aw[tid][2] = e2 * inv; aw[tid][3] = e3 * inv;
  }
  __syncthreads();
  #pragma unroll
  for (int it = 0; it < 3; ++it) {
    const int idx = tid + it * 256;
    const int n = idx >> 6;
    float acc = aw[n][3] * rv[b * HDIM + idx];
    if (l > 0)       acc += aw[n][0] * b2f(v[base - HDIM + idx]);
    acc += aw[n][1] * b2f(v[base + idx]);
    if (l < SEQ - 1) acc += aw[n][2] * b2f(v[base + HDIM + idx]);
    att[base + idx] = f2b(acc);
  }
}

// Star (relay) attention (R0 version): per (b,head) block; 1025 keys.
__global__ __launch_bounds__(256) void msa2_attn_k(
    const float* __restrict__ q2, const float* __restrict__ rk2,
    const float* __restrict__ rv2, const u16* __restrict__ k2,
    const u16* __restrict__ v2, const int* __restrict__ src,
    float* __restrict__ att) {
  __shared__ float qs[HD];
  __shared__ float sc[SEQ + 1];
  __shared__ float red[4];
  const int bid = blockIdx.x;
  const int b = bid / NHEAD, n = bid % NHEAD;
  const int tid = threadIdx.x;
  const int hb = b * HDIM + n * HD;
  if (tid < HD) qs[tid] = q2[hb + tid];
  __syncthreads();
  float lmax = -1e30f;
  for (int s = tid; s <= SEQ; s += 256) {
    float sco;
    if (s == 0) {
      float a = 0.f;
      #pragma unroll
      for (int d = 0; d < HD; ++d) a += qs[d] * rk2[hb + d];
      sco = a * ATT_SCALE;
    } else {
      const int l = s - 1;
      if (src[(b * SEQ + l) * 3] == 0) {
        sco = -1e30f;
      } else {
        const u16* kp = k2 + ((size_t)b * SEQ + l) * HDIM + n * HD;
        float a = 0.f;
        #pragma unroll
        for (int d = 0; d < HD; ++d) a += qs[d] * b2f(kp[d]);
        sco = a * ATT_SCALE;
      }
    }
    sc[s] = sco;
    lmax = fmaxf(lmax, sco);
  }
  lmax = blk_max(lmax, red);
  float lsum = 0.f;
  for (int s = tid; s <= SEQ; s += 256) {
    const float e = __expf(sc[s] - lmax);
    sc[s] = e;
    lsum += e;
  }
  lsum = blk_sum(lsum, red);
  if (tid < HD) {
    const float inv = 1.0f / lsum;
    float acc = sc[0] * rv2[hb + tid];
    const u16* vp = v2 + (size_t)b * SEQ * HDIM + n * HD + tid;
    for (int l = 0; l < SEQ; ++l) acc += sc[l + 1] * b2f(vp[(size_t)l * HDIM]);
    att[hb + tid] = acc * inv;
  }
}

// Relay projections: one wave per (mat, n) WEIGHT ROW; accumulate 8 batches.
__global__ __launch_bounds__(256) void relay_proj_k(
    const float* __restrict__ A, int N, int nm,
    const float* W0, const float* W1, const float* W2,
    const float* b0, const float* b1, const float* b2v,
    float* O0, float* O1, float* O2, int act) {
  const int wid = blockIdx.x * 4 + (threadIdx.x >> 6);
  const int lane = threadIdx.x & 63;
  const int mat = wid / N, n = wid % N;
  const float* W  = mat == 0 ? W0 : (mat == 1 ? W1 : W2);
  const float* bb = mat == 0 ? b0 : (mat == 1 ? b1 : b2v);
  float* O        = mat == 0 ? O0 : (mat == 1 ? O1 : O2);
  const float4* wr = (const float4*)(W + (size_t)n * HDIM);
  float acc[NB] = {};
  #pragma unroll
  for (int it = 0; it < 3; ++it) {
    const int k4 = it * 64 + lane;
    const float4 wv = wr[k4];
    #pragma unroll
    for (int b = 0; b < NB; ++b) {
      const float4 av = *(const float4*)&A[b * HDIM + k4 * 4];
      acc[b] += av.x * wv.x + av.y * wv.y + av.z * wv.z + av.w * wv.w;
    }
  }
  #pragma unroll
  for (int b = 0; b < NB; ++b) {
    float a = acc[b];
    #pragma unroll
    for (int off = 32; off > 0; off >>= 1) a += __shfl_down(a, off, 64);
    if (lane == 0) {
      float v = a + bb[n];
      if (act == 2) v = v > 0.f ? v : 0.01f * v;
      O[(size_t)b * N + n] = v;
    }
  }
}

// ft[b] = [relay[b] ; nodes[b, positions[b]]]
__global__ __launch_bounds__(256) void ft_k(
    const float* __restrict__ relay, const float* __restrict__ nodes,
    const int* __restrict__ positions, float* __restrict__ ft) {
  const int gid = blockIdx.x * 256 + threadIdx.x;
  const int b = gid / 1536, j = gid % 1536;
  if (j < HDIM) {
    ft[gid] = relay[b * HDIM + j];
  } else {
    const int p = positions[b];
    ft[gid] = nodes[((size_t)b * SEQ + p) * HDIM + (j - HDIM)];
  }
}

// head1: one wave per (j,o) weight row; ft (8x1536 = 48 KB) in LDS.
__global__ __launch_bounds__(256) void head1_k(
    const float* __restrict__ ft, const float* __restrict__ w,
    const float* __restrict__ bias, float* __restrict__ hid) {
  __shared__ float fs[NB * 1536];
  const int j = blockIdx.y;
  {
    const float4* s4 = (const float4*)ft;
    float4* d4 = (float4*)fs;
    for (int i = threadIdx.x; i < (NB * 1536) / 4; i += 256) d4[i] = s4[i];
  }
  __syncthreads();
  const int wave = threadIdx.x >> 6, lane = threadIdx.x & 63;
  const int o = blockIdx.x * 4 + wave;
  const float4* wr = (const float4*)(w + ((size_t)j * NHID + o) * 1536);
  float acc[NB] = {};
  #pragma unroll
  for (int it = 0; it < 6; ++it) {
    const int k4 = it * 64 + lane;
    const float4 wv = wr[k4];
    #pragma unroll
    for (int b = 0; b < NB; ++b) {
      const float4 hv = *(const float4*)&fs[b * 1536 + k4 * 4];
      acc[b] += hv.x * wv.x + hv.y * wv.y + hv.z * wv.z + hv.w * wv.w;
    }
  }
  #pragma unroll
  for (int b = 0; b < NB; ++b) {
    float a = acc[b];
    #pragma unroll
    for (int off = 32; off > 0; off >>= 1) a += __shfl_down(a, off, 64);
    if (lane == 0)
      hid[((size_t)j * NB + b) * NHID + o] = fmaxf(a + bias[j * NHID + o], 0.f);
  }
}

// head2: one wave per (j,o) weight row; hid[j] (8x1024 = 32 KB) in LDS.
__global__ __launch_bounds__(256) void head2_k(
    const float* __restrict__ hid, const float* __restrict__ w,
    const float* __restrict__ bias, float* __restrict__ out) {
  __shared__ float hs[NB * NHID];
  const int j = blockIdx.y;
  {
    const float4* s4 = (const float4*)(hid + (size_t)j * NB * NHID);
    float4* d4 = (float4*)hs;
    for (int i = threadIdx.x; i < (NB * NHID) / 4; i += 256) d4[i] = s4[i];
  }
  __syncthreads();
  const int wave = threadIdx.x >> 6, lane = threadIdx.x & 63;
  const int o = blockIdx.x * 4 + wave;
  const float4* wr = (const float4*)(w + ((size_t)j * NOUT + o) * NHID);
  float acc[NB] = {};
  #pragma unroll
  for (int it = 0; it < 4; ++it) {
    const int k4 = it * 64 + lane;
    const float4 wv = wr[k4];
    #pragma unroll
    for (int b = 0; b < NB; ++b) {
      const float4 hv = *(const float4*)&hs[b * NHID + k4 * 4];
      acc[b] += hv.x * wv.x + hv.y * wv.y + hv.z * wv.z + hv.w * wv.w;
    }
  }
  #pragma unroll
  for (int b = 0; b < NB; ++b) {
    float a = acc[b];
    #pragma unroll
    for (int off = 32; off > 0; off >>= 1) a += __shfl_down(a, off, 64);
    if (lane == 0)
      out[(size_t)(b * 3 + j) * NOUT + o] = a + bias[j * NOUT + o];
  }
}

// ---------------------------------------------------------------------------
extern "C" void kernel_launch(void* const* d_in, const int* in_sizes, int n_in,
                              void* d_out, int out_size, void* d_ws, size_t ws_size,
                              hipStream_t stream) {
  (void)in_sizes; (void)n_in; (void)out_size; (void)ws_size;
  const int* src       = (const int*)d_in[0];
  const int* positions = (const int*)d_in[1];
  const float* emb   = (const float*)d_in[2];
  const float* pt    = (const float*)d_in[3];
  const float* norm_g = (const float*)d_in[4]; const float* norm_b = (const float*)d_in[5];
  const float* pw_w1 = (const float*)d_in[6];  const float* pw_b1 = (const float*)d_in[7];
  const float* pw_w2 = (const float*)d_in[8];  const float* pw_b2 = (const float*)d_in[9];
  const float* pw_g  = (const float*)d_in[10]; const float* pw_bn = (const float*)d_in[11];
  const float* ring_wq = (const float*)d_in[12]; const float* ring_bq = (const float*)d_in[13];
  const float* ring_wk = (const float*)d_in[14]; const float* ring_bk = (const float*)d_in[15];
  const float* ring_wv = (const float*)d_in[16]; const float* ring_bv = (const float*)d_in[17];
  const float* ring_wo = (const float*)d_in[18]; const float* ring_bo = (const float*)d_in[19];
  const float* star_wq = (const float*)d_in[20]; const float* star_bq = (const float*)d_in[21];
  const float* star_wk = (const float*)d_in[22]; const float* star_bk = (const float*)d_in[23];
  const float* star_wv = (const float*)d_in[24]; const float* star_bv = (const float*)d_in[25];
  const float* star_wo = (const float*)d_in[26]; const float* star_bo = (const float*)d_in[27];
  const float* head_w1 = (const float*)d_in[28]; const float* head_b1 = (const float*)d_in[29];
  const float* head_w2 = (const float*)d_in[30]; const float* head_b2 = (const float*)d_in[31];

  // ---------------- workspace: 8 units of NTOK*2 bytes (12.58 MB) ----------
  char* ws = (char*)d_ws;
  const size_t NTOK = (size_t)NB * SEQ * HDIM;            // 6,291,456 elems
  const size_t U = NTOK * 2;                              // unit = 12,582,912 B
  float* nodes   = (float*)(ws);                          // U0,U1 (fp32)
  u16* inner     = (u16*)(ws + 2 * U);                    // U2..U5 [M][3072]
  u16* prelnA    = (u16*)(ws + 6 * U);                    // U6
  u16* hbuf      = (u16*)(ws + 2 * U);                    // U2
  u16* qb        = (u16*)(ws + 3 * U);                    // U3
  u16* kb        = (u16*)(ws + 4 * U);                    // U4
  u16* vb        = (u16*)(ws + 5 * U);                    // U5
  u16* attb      = (u16*)(ws + 6 * U);                    // U6 (prelnA dead)
  u16* prelnB    = (u16*)(ws + 3 * U);                    // U3 (qb dead)
  u16* nodes_b16 = (u16*)(ws + 7 * U);                    // U7
  u16* k2b       = (u16*)(ws + 4 * U);                    // U4 (phase C)
  u16* v2b       = (u16*)(ws + 5 * U);                    // U5 (phase C)
  u16* wc        = (u16*)(ws + 8 * U);                    // 9,437,184 B weight-cvt
  char* small    = ws + 8 * U + 9437184;
  float* part  = (float*)(small);                          // 393,216
  float* relay = (float*)(small + 393216);
  float* sb0 = (float*)(small + 393216 + 1 * 24576);
  float* sb1 = (float*)(small + 393216 + 2 * 24576);
  float* sb2 = (float*)(small + 393216 + 3 * 24576);
  float* sb3 = (float*)(small + 393216 + 4 * 24576);
  float* ftb = (float*)(small + 393216 + 5 * 24576);
  float* hid = (float*)(small + 393216 + 5 * 24576 + 49152);

  embed_k<<<NB * SEQ, 256, 0, stream>>>(src, emb, pt, nodes, nodes_b16);
  relay_mean1_k<<<dim3(3, 16, NB), 256, 0, stream>>>(nodes, part);
  relay_mean2_k<<<dim3(3, NB), 256, 0, stream>>>(part, relay);

  const int NW1 = DINNER * HDIM;   // 2,359,296 elems per layer slice
  const int NQK = HDIM * HDIM;     // 589,824
  const int M = NB * SEQ;          // 8192

  for (int i = 0; i < 2; ++i) {
    const float* pw_w1_l = pw_w1 + (size_t)i * NW1;
    const float* pw_w2_l = pw_w2 + (size_t)i * NW1;
    const float* pw_b1_l = pw_b1 + (size_t)i * DINNER;
    const float* pw_b2_l = pw_b2 + (size_t)i * HDIM;
    const float* pw_g_l  = pw_g + (size_t)i * HDIM;
    const float* pw_bn_l = pw_bn + (size_t)i * HDIM;
    const float* ng_l = norm_g + (size_t)i * HDIM;
    const float* nb_l = norm_b + (size_t)i * HDIM;
    const float* rwq = ring_wq + (size_t)i * NQK; const float* rbq = ring_bq + (size_t)i * HDIM;
    const float* rwk = ring_wk + (size_t)i * NQK; const float* rbk = ring_bk + (size_t)i * HDIM;
    const float* rwv = ring_wv + (size_t)i * NQK; const float* rbv = ring_bv + (size_t)i * HDIM;
    const float* rwo = ring_wo + (size_t)i * NQK; const float* rbo = ring_bo + (size_t)i * HDIM;
    const float* swq = star_wq + (size_t)i * NQK; const float* sbq = star_bq + (size_t)i * HDIM;
    const float* swk = star_wk + (size_t)i * NQK; const float* sbk = star_bk + (size_t)i * HDIM;
    const float* swv = star_wv + (size_t)i * NQK; const float* sbv = star_bv + (size_t)i * HDIM;
    const float* swo = star_wo + (size_t)i * NQK; const float* sbo = star_bo + (size_t)i * HDIM;

    // ---- phase A: FFN ----
    u16* wc_pw1 = wc;
    u16* wc_pw2 = wc + NW1;
    {
      Cvt4 a = { pw_w1_l, pw_w2_l, pw_w1_l, pw_w1_l,
                 wc_pw1, wc_pw2, wc_pw1, wc_pw1,
                 NW1 / 4, NW1 / 2, NW1 / 2, NW1 / 2 };
      cvt4_k<<<(NW1 / 2 + 255) / 256, 256, 0, stream>>>(a);
    }
    gemm_bt<1, 128><<<dim3(DINNER / 128, M / 128), 256, 0, stream>>>(
        nodes_b16, wc_pw1, wc_pw1, wc_pw1, pw_b1_l, pw_b1_l, pw_b1_l,
        inner, inner, inner, M, DINNER, HDIM);
    gemm_bt<0, 64><<<dim3(HDIM / 128, M / 64), 256, 0, stream>>>(
        inner, wc_pw2, wc_pw2, wc_pw2, pw_b2_l, pw_b2_l, pw_b2_l,
        prelnA, prelnA, prelnA, M, HDIM, DINNER);
    // inner dead; hbuf=U2 safe to write.
    ln_resid_k<<<M, 256, 0, stream>>>(prelnA, nodes, pw_g_l, pw_bn_l, hbuf);

    // ---- phase B: ring attention ----
    u16* wc_rq = wc;
    u16* wc_rk = wc + NQK;
    u16* wc_rv = wc + 2 * NQK;
    u16* wc_ro = wc + 3 * NQK;
    {
      Cvt4 a = { rwq, rwk, rwv, rwo, wc_rq, wc_rk, wc_rv, wc_ro,
                 NQK / 4, NQK / 2, 3 * NQK / 4, NQK };
      cvt4_k<<<(NQK + 255) / 256, 256, 0, stream>>>(a);
    }
    // fused q,k,v: grid.x = 3 * 6 = 18; reads hbuf(U2), writes U3,U4,U5
    gemm_bt<0, 64><<<dim3(3 * (HDIM / 128), M / 64), 256, 0, stream>>>(
        hbuf, wc_rq, wc_rk, wc_rv, rbq, rbk, rbv,
        qb, kb, vb, M, HDIM, HDIM);
    relay_proj_k<<<2 * HDIM / 4, 256, 0, stream>>>(
        relay, HDIM, 2, rwk, rwv, rwk, rbk, rbv, rbk, sb0, sb1, sb2, 0);
    ring_attn_k<<<NB * SEQ, 256, 0, stream>>>(qb, kb, vb, sb0, sb1, attb);
    // qb(U3) dead -> prelnB
    gemm_bt<0, 64><<<dim3(HDIM / 128, M / 64), 256, 0, stream>>>(
        attb, wc_ro, wc_ro, wc_ro, rbo, rbo, rbo,
        prelnB, prelnB, prelnB, M, HDIM, HDIM);
    ln_leaky_mask_k<<<M, 256, 0, stream>>>(prelnB, ng_l, nb_l, src, nodes, nodes_b16);

    // ---- phase C: star attention ----
    u16* wc_sk = wc;
    u16* wc_sv = wc + NQK;
    {
      Cvt4 a = { swk, swv, swk, swk, wc_sk, wc_sv, wc_sk, wc_sk,
                 NQK / 4, NQK / 2, NQK / 2, NQK / 2 };
      cvt4_k<<<(NQK / 2 + 255) / 256, 256, 0, stream>>>(a);
    }
    // fused k2,v2: grid.x = 2 * 6 = 12; reads nodes_b16(U7), writes U4,U5
    gemm_bt<0, 64><<<dim3(2 * (HDIM / 128), M / 64), 256, 0, stream>>>(
        nodes_b16, wc_sk, wc_sv, wc_sv, sbk, sbv, sbv,
        k2b, v2b, v2b, M, HDIM, HDIM);
    relay_proj_k<<<3 * HDIM / 4, 256, 0, stream>>>(
        relay, HDIM, 3, swq, swk, swv, sbq, sbk, sbv, sb0, sb1, sb2, 0);
    msa2_attn_k<<<NB * NHEAD, 256, 0, stream>>>(sb0, sb1, sb2, k2b, v2b, src, sb3);
    relay_proj_k<<<HDIM / 4, 256, 0, stream>>>(
        sb3, HDIM, 1, swo, swo, swo, sbo, sbo, sbo, relay, sb1, sb2, 2);
  }

  ft_k<<<48, 256, 0, stream>>>(relay, nodes, positions, ftb);
  head1_k<<<dim3(NHID / 4, 3), 256, 0, stream>>>(ftb, head_w1, head_b1, hid);
  head2_k<<<dim3(NOUT / 4, 3), 256, 0, stream>>>(hid, head_w2, head_b2, (float*)d_out);
}